// Round 13
// baseline (221.779 us; speedup 1.0000x reference)
//
#include <hip/hip_runtime.h>
#include <hip/hip_bf16.h>
#include <math.h>

#define C 384
#define NF 16
#define H 256
#define Bb 4
#define Kk 2048
#define Nn 16384
#define MB 64           // nodes per block (2 m-tiles of 32)
#define LDA 392         // act row stride in shorts

typedef __attribute__((ext_vector_type(8)))  short bf16x8;
typedef __attribute__((ext_vector_type(4)))  float f32x4;
typedef __attribute__((ext_vector_type(16))) float f32x16;
typedef __attribute__((ext_vector_type(4)))  short s16x4;

// ws layout (shorts), fragment-linear 32-tiles: [tile32][kchunk16][lane(64)][8]
#define POS_OFF 0            // pos_w  F=384 K=32
#define Q1_OFF  12288        // q_w1*q_ln_g   F=384 K=384
#define Q2_OFF  159744       // q_w2          F=384 K=384
#define M1_OFF  307200       // m_w1*m_ln_g   F=256 K=384
#define M2_OFF  405504       // m_w2          F=256 K=256
#define M3_OFF  471040       // m_w3 padded [32][256]
#define W_TOTAL 479232
#define NCONV   ((W_TOTAL + 255) / 256)
// float constants after the shorts
#define GQ_OFF 0
#define CQ_OFF 384
#define GM_OFF 768
#define CM_OFF 1024

// barrier that does NOT drain vmcnt — weight prefetches stay in flight.
#define BAR() __asm__ volatile("s_waitcnt lgkmcnt(0)\ns_barrier" ::: "memory")

__device__ __attribute__((always_inline)) inline short f2bf(float x) {
    return __builtin_bit_cast(short, __float2bfloat16(x));
}
__device__ __attribute__((always_inline)) inline float bf2f(short s) {
    return __bfloat162float(__builtin_bit_cast(__hip_bfloat16, s));
}
__device__ __attribute__((always_inline)) inline float silu(float v) {
    return v * __builtin_amdgcn_rcpf(1.f + __expf(-v));
}
__device__ __attribute__((always_inline)) inline s16x4 pack4(f32x4 v) {
    __hip_bfloat162 p0 = __float22bfloat162_rn(float2{v[0], v[1]});
    __hip_bfloat162 p1 = __float22bfloat162_rn(float2{v[2], v[3]});
    s16x4 o;
    o[0] = __builtin_bit_cast(short, p0.x);
    o[1] = __builtin_bit_cast(short, p0.y);
    o[2] = __builtin_bit_cast(short, p1.x);
    o[3] = __builtin_bit_cast(short, p1.y);
    return o;
}

// ---- prep: weight f32->bf16 32-tile fragment swizzle + LN-const fold ----
// chunk = 1KB = [lane(64)][8 shorts]; element (f=tile*32+(lane&31),
// k=kchunk*16+(lane>>5)*8+j)
__global__ __launch_bounds__(256) void prep(
    const float* __restrict__ pos_w, const float* __restrict__ q_w1,
    const float* __restrict__ q_w2,  const float* __restrict__ m_w1,
    const float* __restrict__ m_w2,  const float* __restrict__ m_w3,
    const float* __restrict__ q_ln_g, const float* __restrict__ q_ln_b,
    const float* __restrict__ m_ln_g, const float* __restrict__ m_ln_b,
    const float* __restrict__ q_b1,   const float* __restrict__ m_b1,
    short* __restrict__ ws, float* __restrict__ cst)
{
    __shared__ float rg[4], rc[4];
    int tid = threadIdx.x;
    int blk = blockIdx.x;
    if (blk < NCONV) {
        int i = blk * 256 + tid;
        if (i >= W_TOTAL) return;
        const float* src; int off, K;
        if      (i < Q1_OFF) { src = pos_w; off = POS_OFF; K = 32; }
        else if (i < Q2_OFF) { src = q_w1;  off = Q1_OFF;  K = 384; }
        else if (i < M1_OFF) { src = q_w2;  off = Q2_OFF;  K = 384; }
        else if (i < M2_OFF) { src = m_w1;  off = M1_OFF;  K = 384; }
        else if (i < M3_OFF) { src = m_w2;  off = M2_OFF;  K = 256; }
        else                 { src = m_w3;  off = M3_OFF;  K = 256; }
        int t = i - off;
        int chunk = t >> 9, r = t & 511;
        int lane = r >> 3, j = r & 7;
        int lnn = lane & 31, half = lane >> 5;
        int NKm = K >> 4;
        int ntg = chunk / NKm, kk = chunk - ntg * NKm;
        int f = ntg * 32 + lnn, k = kk * 16 + half * 8 + j;
        float v;
        if (off == M3_OFF) v = (f < 3) ? m_w3[f * 256 + k] : 0.f;
        else               v = src[(size_t)f * K + k];
        if (off == Q1_OFF) v *= q_ln_g[k];
        if (off == M1_OFF) v *= m_ln_g[k];
        ws[i] = f2bf(v);
        return;
    }
    int f = blk - NCONV;   // 0..639
    const float *Wsrc, *lng, *lnb, *bias; int fr, go, co;
    if (f < 384) { Wsrc = q_w1; lng = q_ln_g; lnb = q_ln_b; bias = q_b1; fr = f;      go = GQ_OFF; co = CQ_OFF; }
    else         { Wsrc = m_w1; lng = m_ln_g; lnb = m_ln_b; bias = m_b1; fr = f - 384; go = GM_OFF; co = CM_OFF; }
    float g = 0.f, c = 0.f;
    for (int k = tid; k < 384; k += 256) {
        float wv = Wsrc[(size_t)fr * 384 + k];
        g += bf2f(f2bf(wv * lng[k]));   // match MFMA's bf16-rounded weights
        c += wv * lnb[k];
    }
    #pragma unroll
    for (int d = 1; d < 64; d <<= 1) { g += __shfl_xor(g, d); c += __shfl_xor(c, d); }
    if ((tid & 63) == 0) { rg[tid >> 6] = g; rc[tid >> 6] = c; }
    __syncthreads();
    if (tid == 0) {
        cst[go + fr] = rg[0] + rg[1] + rg[2] + rg[3];
        cst[co + fr] = rc[0] + rc[1] + rc[2] + rc[3] + bias[fr];
    }
}

// In-place FC layer, 32x32x16 MFMA, rotating 4-deep B prefetch (distance-3),
// transposed D (weights as A-op): thread (ln=lane&31, half=lane>>5) holds
// D[f=FB+nt*32+8*(reg>>2)+4*half+(reg&3)][m=mt*32+ln].
template<int K, int NT, int NTN, int KN, bool SILU_, bool MASK, bool LNIN, bool STATS>
__device__ __attribute__((always_inline)) inline void layer_ip(
    const short* __restrict__ W, const float* __restrict__ cb,
    const float* __restrict__ Gf, int FB,
    const short* __restrict__ Wn, int FBn,
    bf16x8 (&bin)[3],
    short (*__restrict__ xs)[LDA],
    float (*__restrict__ sc1)[4], float (*__restrict__ sc2)[4],
    const float* __restrict__ wmask, int w, int lane)
{
    constexpr int NK = K / 16;
    const int ln = lane & 31, half = lane >> 5;
    const short* bp[NT];
    #pragma unroll
    for (int nt = 0; nt < NT; ++nt)
        bp[nt] = W + (size_t)(FB / 32 + nt) * NK * 512 + lane * 8;

    f32x16 acc[2][NT];
    #pragma unroll
    for (int mt = 0; mt < 2; ++mt)
        #pragma unroll
        for (int nt = 0; nt < NT; ++nt)
            acc[mt][nt] = (f32x16)(0.f);

    bf16x8 B[4][NT], a0[2], a1[2];
    #pragma unroll
    for (int nt = 0; nt < NT; ++nt) B[0][nt] = bin[nt];  // chunk 0 (cross-layer)
    #pragma unroll
    for (int nt = 0; nt < NT; ++nt) B[1][nt] = *(const bf16x8*)(bp[nt] + 512);
    #pragma unroll
    for (int nt = 0; nt < NT; ++nt) B[2][nt] = *(const bf16x8*)(bp[nt] + 1024);
    #pragma unroll
    for (int mt = 0; mt < 2; ++mt)
        a0[mt] = *(const bf16x8*)&xs[mt * 32 + ln][half * 8];

    #pragma unroll
    for (int kc = 0; kc < NK; ++kc) {
        if (kc + 3 < NK) {
            #pragma unroll
            for (int nt = 0; nt < NT; ++nt)
                B[(kc + 3) & 3][nt] = *(const bf16x8*)(bp[nt] + (kc + 3) * 512);
        } else if (kc + 3 == NK) {
            // cross-layer prefetch in the distance-3 slot; BAR keeps it alive
            #pragma unroll
            for (int nt = 0; nt < NTN; ++nt)
                bin[nt] = *(const bf16x8*)(Wn + (size_t)(FBn / 32 + nt) * (KN / 16) * 512 + lane * 8);
        }
        bf16x8* ac = (kc & 1) ? a1 : a0;
        bf16x8* an = (kc & 1) ? a0 : a1;
        if (kc + 1 < NK) {
            #pragma unroll
            for (int mt = 0; mt < 2; ++mt)
                an[mt] = *(const bf16x8*)&xs[mt * 32 + ln][(kc + 1) * 16 + half * 8];
        }
        #pragma unroll
        for (int nt = 0; nt < NT; ++nt)
            #pragma unroll
            for (int mt = 0; mt < 2; ++mt)
                acc[mt][nt] = __builtin_amdgcn_mfma_f32_32x32x16_bf16(
                    B[kc & 3][nt], ac[mt], acc[mt][nt], 0, 0, 0);
    }

    BAR();   // all reads of xs complete before any in-place write (lgkm only)

    float mk[2], rstd[2], rm[2];
    #pragma unroll
    for (int mt = 0; mt < 2; ++mt) {
        int m = mt * 32 + ln;
        if (MASK) mk[mt] = wmask[m];
        if (LNIN) {
            f32x4 p1 = *(const f32x4*)&sc1[m][0];
            f32x4 p2 = *(const f32x4*)&sc2[m][0];
            float t1 = p1[0] + p1[1] + p1[2] + p1[3];
            float t2 = p2[0] + p2[1] + p2[2] + p2[3];
            float mean = t1 * (1.f / 384.f);
            float var  = t2 * (1.f / 384.f) - mean * mean;
            rstd[mt] = rsqrtf(var + 1e-5f);
            rm[mt]   = rstd[mt] * mean;
        }
    }

    float s1[2] = {0.f, 0.f}, s2[2] = {0.f, 0.f};
    #pragma unroll
    for (int nt = 0; nt < NT; ++nt) {
        #pragma unroll
        for (int g = 0; g < 4; ++g) {
            const int f0 = FB + nt * 32 + 8 * g + 4 * half;
            f32x4 c4 = *(const f32x4*)&cb[f0];
            f32x4 g4;
            if (LNIN) g4 = *(const f32x4*)&Gf[f0];
            #pragma unroll
            for (int mt = 0; mt < 2; ++mt) {
                f32x4 vv;
                #pragma unroll
                for (int i = 0; i < 4; ++i) {
                    float av = acc[mt][nt][4 * g + i];
                    float v;
                    if (LNIN) v = fmaf(rstd[mt], av, fmaf(-rm[mt], g4[i], c4[i]));
                    else      v = av + c4[i];
                    if (SILU_) v = silu(v);
                    if (MASK) v *= mk[mt];
                    if (STATS) { s1[mt] += v; s2[mt] += v * v; }
                    vv[i] = v;
                }
                *(s16x4*)&xs[mt * 32 + ln][f0] = pack4(vv);
            }
        }
    }
    if (STATS) {
        #pragma unroll
        for (int mt = 0; mt < 2; ++mt) {
            s1[mt] += __shfl_xor(s1[mt], 32);
            s2[mt] += __shfl_xor(s2[mt], 32);
        }
        if (half == 0) {
            #pragma unroll
            for (int mt = 0; mt < 2; ++mt) {
                sc1[mt * 32 + ln][w] = s1[mt];
                sc2[mt * 32 + ln][w] = s2[mt];
            }
        }
    }
    BAR();   // writes (xs and sc) visible before next layer
}

__global__ __launch_bounds__(256, 2) void upxi64(
    const float* __restrict__ s_parent, const float* __restrict__ mu_k,
    const float* __restrict__ R_k,      const float* __restrict__ s_k,
    const int*   __restrict__ a_idx,    const float* __restrict__ node_mask,
    const float* __restrict__ pos01,
    const float* __restrict__ pos_b,
    const float* __restrict__ q_b2,     const float* __restrict__ m_b2,
    const float* __restrict__ m_b3,
    const short* __restrict__ wsb,      const float* __restrict__ cst,
    float* __restrict__ out)
{
    __shared__ short xs[MB][LDA];
    __shared__ float sc1[MB][4];
    __shared__ float sc2[MB][4];
    __shared__ float wmask[MB], wpos[MB];
    __shared__ int   widx[MB];

    const int tid  = threadIdx.x;
    const int w    = tid >> 6;
    const int lane = tid & 63;
    const int ln   = lane & 31;
    const int half = lane >> 5;

    const int g0 = blockIdx.x * MB;
    const int b  = g0 / Nn;
    const int n0 = g0 % Nn;

    // prefetch Q1 first k-chunk immediately (hidden under scalars+sincos+pos)
    bf16x8 bin[3];
    #pragma unroll
    for (int nt = 0; nt < 3; ++nt)
        bin[nt] = *(const bf16x8*)(wsb + Q1_OFF + (size_t)(w * 3 + nt) * 24 * 512 + lane * 8);

    if (tid < MB) {
        int gi = b * Nn + n0 + tid;
        int idx = a_idx[gi];
        widx[tid]  = min(max(idx, 0), Kk - 1);
        wmask[tid] = node_mask[gi];
        wpos[tid]  = pos01[gi];
    }
    BAR();

    const float* gbase = s_parent + (long)b * Kk * C;

    // ---- pos layer (32x32, transposed D): pos_w as A-op, feats as B-op ----
    // B[k][n]: n=lane&31, k=half*8+j per chunk; chunk0 k=0..15 (sin),
    // chunk1 k=16..31 (cos) — same freq half*8+j for both.
    {
        const short* pos_wb = wsb + POS_OFF;
        bf16x8 wf[3][2];
        #pragma unroll
        for (int nt = 0; nt < 3; ++nt)
            #pragma unroll
            for (int kc = 0; kc < 2; ++kc)
                wf[nt][kc] = *(const bf16x8*)&pos_wb[((w * 3 + nt) * 2 + kc) * 512 + lane * 8];
        bf16x8 bs[2], bc[2];
        #pragma unroll
        for (int mt = 0; mt < 2; ++mt) {
            float p = wpos[mt * 32 + ln];
            #pragma unroll
            for (int j = 0; j < 8; ++j) {
                int fi = half * 8 + j;
                float fr = (float)(1 << fi) * 3.14159265358979323846f;
                float sv, cv;
                __sincosf(p * fr, &sv, &cv);
                bs[mt][j] = f2bf(sv);
                bc[mt][j] = f2bf(cv);
            }
        }
        f32x16 acc[2][3];
        #pragma unroll
        for (int mt = 0; mt < 2; ++mt)
            #pragma unroll
            for (int nt = 0; nt < 3; ++nt)
                acc[mt][nt] = (f32x16)(0.f);
        #pragma unroll
        for (int nt = 0; nt < 3; ++nt)
            #pragma unroll
            for (int mt = 0; mt < 2; ++mt) {
                acc[mt][nt] = __builtin_amdgcn_mfma_f32_32x32x16_bf16(wf[nt][0], bs[mt], acc[mt][nt], 0, 0, 0);
                acc[mt][nt] = __builtin_amdgcn_mfma_f32_32x32x16_bf16(wf[nt][1], bc[mt], acc[mt][nt], 0, 0, 0);
            }
        float mk[2]; int ix[2];
        #pragma unroll
        for (int mt = 0; mt < 2; ++mt) {
            mk[mt] = wmask[mt * 32 + ln];
            ix[mt] = widx[mt * 32 + ln];
        }
        float s1[2] = {0.f, 0.f}, s2[2] = {0.f, 0.f};
        #pragma unroll
        for (int nt = 0; nt < 3; ++nt) {
            #pragma unroll
            for (int g = 0; g < 4; ++g) {
                const int f0 = w * 96 + nt * 32 + 8 * g + 4 * half;
                f32x4 pb4 = *(const f32x4*)&pos_b[f0];
                #pragma unroll
                for (int mt = 0; mt < 2; ++mt) {
                    f32x4 g4 = *(const f32x4*)&gbase[(long)ix[mt] * C + f0];
                    f32x4 vv;
                    #pragma unroll
                    for (int i = 0; i < 4; ++i) {
                        float v = (acc[mt][nt][4 * g + i] + pb4[i]) * mk[mt] + g4[i];
                        s1[mt] += v; s2[mt] += v * v;
                        vv[i] = v;
                    }
                    *(s16x4*)&xs[mt * 32 + ln][f0] = pack4(vv);
                }
            }
        }
        #pragma unroll
        for (int mt = 0; mt < 2; ++mt) {
            s1[mt] += __shfl_xor(s1[mt], 32);
            s2[mt] += __shfl_xor(s2[mt], 32);
        }
        if (half == 0) {
            #pragma unroll
            for (int mt = 0; mt < 2; ++mt) {
                sc1[mt * 32 + ln][w] = s1[mt];
                sc2[mt * 32 + ln][w] = s2[mt];
            }
        }
    }
    BAR();

    // Q1: LN(q) folded: v = silu(rstd*acc - rm*Gq + Cq)
    layer_ip<384, 3, 3, 384, true,  false, true,  false>(wsb + Q1_OFF, cst + CQ_OFF,
        cst + GQ_OFF, w * 96, wsb + Q2_OFF, w * 96, bin, xs, sc1, sc2, wmask, w, lane);
    // Q2: (acc + b2)*mask, stats for m-LN
    layer_ip<384, 3, 2, 384, false, true,  false, true >(wsb + Q2_OFF, q_b2,
        nullptr, w * 96, wsb + M1_OFF, w * 64, bin, xs, sc1, sc2, wmask, w, lane);
    // M1: LN(m) folded: v = silu(rstd*acc - rm*Gm + Cm)
    layer_ip<384, 2, 2, 256, true,  false, true,  false>(wsb + M1_OFF, cst + CM_OFF,
        cst + GM_OFF, w * 64, wsb + M2_OFF, w * 64, bin, xs, sc1, sc2, wmask, w, lane);
    // M2: silu(acc + b2)
    layer_ip<256, 2, 1, 256, true,  false, false, false>(wsb + M2_OFF, m_b2,
        nullptr, w * 64, wsb + M3_OFF, 0, bin, xs, sc1, sc2, wmask, w, lane);

    // ---- tail: 256->3 via padded 32-tile MFMA (waves 0,1 own m-tiles), tanh*1.5 ----
    if (w < 2) {
        const short* W3 = wsb + M3_OFF;
        f32x16 a3 = (f32x16)(0.f);
        #pragma unroll
        for (int kc = 0; kc < 16; ++kc) {
            bf16x8 a  = *(const bf16x8*)&xs[w * 32 + ln][kc * 16 + half * 8];
            bf16x8 bf = (kc == 0) ? bin[0]
                      : *(const bf16x8*)(W3 + kc * 512 + lane * 8);
            a3 = __builtin_amdgcn_mfma_f32_32x32x16_bf16(bf, a, a3, 0, 0, 0);
        }
        if (half == 0) {
            int m = w * 32 + ln;
            float mkv = wmask[m];
            #pragma unroll
            for (int r = 0; r < 3; ++r) {   // row = (reg&3) at g=0, half=0
                float v = (a3[r] + m_b3[r]) * mkv;
                sc1[m][r] = tanhf(v) * 1.5f;
            }
        }
        // ---- rigid apply + outputs (same lane wrote sc1[m][*] above) ----
        {
            int m = w * 32 + ln;   // lanes 0..31 read their own node; half==1 dup-safe? no:
            if (half == 0) {
                long gi = (long)b * Nn + n0 + m;
                long pk = (long)b * Kk + widx[m];
                float mkv = wmask[m];
                float xv[3], yv[3], xiv[3];
                #pragma unroll
                for (int j = 0; j < 3; ++j) {
                    xiv[j] = sc1[m][j];
                    float sc = fmaxf(s_k[pk * 3 + j], 1e-8f);
                    xv[j] = xiv[j] * sc;
                }
                #pragma unroll
                for (int i = 0; i < 3; ++i) {
                    float a = R_k[pk * 9 + i * 3 + 0] * xv[0]
                            + R_k[pk * 9 + i * 3 + 1] * xv[1]
                            + R_k[pk * 9 + i * 3 + 2] * xv[2]
                            + mu_k[pk * 3 + i];
                    yv[i] = a * mkv * 10.f;
                }
                float* o0 = out;
                float* o1 = out + (long)Bb * Nn * 3;
                float* o2 = out + (long)Bb * Nn * 6;
                #pragma unroll
                for (int j = 0; j < 3; ++j) { o0[gi * 3 + j] = xiv[j]; o1[gi * 3 + j] = yv[j]; }
                o2[gi] = wpos[m];
            }
        }
    }
}

extern "C" void kernel_launch(void* const* d_in, const int* in_sizes, int n_in,
                              void* d_out, int out_size, void* d_ws, size_t ws_size,
                              hipStream_t stream) {
    const float* s_parent = (const float*)d_in[0];
    const float* mu_k     = (const float*)d_in[1];
    const float* R_k      = (const float*)d_in[2];
    const float* s_k      = (const float*)d_in[3];
    const int*   a_idx    = (const int*)  d_in[4];
    const float* node_mask= (const float*)d_in[5];
    const float* pos01    = (const float*)d_in[6];
    const float* pos_w    = (const float*)d_in[7];
    const float* pos_b    = (const float*)d_in[8];
    const float* q_ln_g   = (const float*)d_in[9];
    const float* q_ln_b   = (const float*)d_in[10];
    const float* q_w1     = (const float*)d_in[11];
    const float* q_b1     = (const float*)d_in[12];
    const float* q_w2     = (const float*)d_in[13];
    const float* q_b2     = (const float*)d_in[14];
    const float* m_ln_g   = (const float*)d_in[15];
    const float* m_ln_b   = (const float*)d_in[16];
    const float* m_w1     = (const float*)d_in[17];
    const float* m_b1     = (const float*)d_in[18];
    const float* m_w2     = (const float*)d_in[19];
    const float* m_b2     = (const float*)d_in[20];
    const float* m_w3     = (const float*)d_in[21];
    const float* m_b3     = (const float*)d_in[22];

    short* wsb = (short*)d_ws;
    float* cst = (float*)(wsb + W_TOTAL);

    prep<<<NCONV + 640, 256, 0, stream>>>(
        pos_w, q_w1, q_w2, m_w1, m_w2, m_w3,
        q_ln_g, q_ln_b, m_ln_g, m_ln_b, q_b1, m_b1, wsb, cst);

    int blocks = (Bb * Nn) / MB;  // 1024
    upxi64<<<blocks, 256, 0, stream>>>(
        s_parent, mu_k, R_k, s_k, a_idx, node_mask, pos01,
        pos_b, q_b2, m_b2, m_b3, wsb, cst, (float*)d_out);
}

// Round 14
// 203.862 us; speedup vs baseline: 1.0879x; 1.0879x over previous
//
#include <hip/hip_runtime.h>
#include <hip/hip_bf16.h>
#include <math.h>

#define C 384
#define NF 16
#define H 256
#define Bb 4
#define Kk 2048
#define Nn 16384
#define MB 64           // nodes per block (4 m-tiles)
#define LDA 392         // act row stride in shorts

typedef __attribute__((ext_vector_type(8))) short bf16x8;
typedef __attribute__((ext_vector_type(4))) float f32x4;
typedef __attribute__((ext_vector_type(4))) short s16x4;

// ws layout (shorts), chunk-major fragment-linear: [kchunk][ftile][ln16][kq32]
#define POS_OFF 0            // pos_w  F=384 K=32
#define Q1_OFF  12288        // q_w1*q_ln_g   F=384 K=384
#define Q2_OFF  159744       // q_w2          F=384 K=384
#define M1_OFF  307200       // m_w1*m_ln_g   F=256 K=384
#define M2_OFF  405504       // m_w2          F=256 K=256
#define M3_OFF  471040       // m_w3 padded [16][256]
#define W_TOTAL 475136
#define NCONV   ((W_TOTAL + 255) / 256)
// float constants after the shorts
#define GQ_OFF 0
#define CQ_OFF 384
#define GM_OFF 768
#define CM_OFF 1024

// barrier that does NOT drain vmcnt — weight prefetches stay in flight.
#define BAR() __asm__ volatile("s_waitcnt lgkmcnt(0)\ns_barrier" ::: "memory")

__device__ __attribute__((always_inline)) inline short f2bf(float x) {
    return __builtin_bit_cast(short, __float2bfloat16(x));
}
__device__ __attribute__((always_inline)) inline float bf2f(short s) {
    return __bfloat162float(__builtin_bit_cast(__hip_bfloat16, s));
}
__device__ __attribute__((always_inline)) inline float silu(float v) {
    return v * __builtin_amdgcn_rcpf(1.f + __expf(-v));
}
__device__ __attribute__((always_inline)) inline s16x4 pack4(f32x4 v) {
    __hip_bfloat162 p0 = __float22bfloat162_rn(float2{v[0], v[1]});
    __hip_bfloat162 p1 = __float22bfloat162_rn(float2{v[2], v[3]});
    s16x4 o;
    o[0] = __builtin_bit_cast(short, p0.x);
    o[1] = __builtin_bit_cast(short, p0.y);
    o[2] = __builtin_bit_cast(short, p1.x);
    o[3] = __builtin_bit_cast(short, p1.y);
    return o;
}

// ---- prep: f32->bf16 chunk-major fragment swizzle + LN-const fold ----
// chunk = kc*FT + ftile; within chunk: [ln(16)][kq(32)].
__global__ __launch_bounds__(256) void prep(
    const float* __restrict__ pos_w, const float* __restrict__ q_w1,
    const float* __restrict__ q_w2,  const float* __restrict__ m_w1,
    const float* __restrict__ m_w2,  const float* __restrict__ m_w3,
    const float* __restrict__ q_ln_g, const float* __restrict__ q_ln_b,
    const float* __restrict__ m_ln_g, const float* __restrict__ m_ln_b,
    const float* __restrict__ q_b1,   const float* __restrict__ m_b1,
    short* __restrict__ ws, float* __restrict__ cst)
{
    __shared__ float rg[4], rc[4];
    int tid = threadIdx.x;
    int blk = blockIdx.x;
    if (blk < NCONV) {
        int i = blk * 256 + tid;
        if (i >= W_TOTAL) return;
        const float* src; int off, K, F;
        if      (i < Q1_OFF) { src = pos_w; off = POS_OFF; K = 32;  F = 384; }
        else if (i < Q2_OFF) { src = q_w1;  off = Q1_OFF;  K = 384; F = 384; }
        else if (i < M1_OFF) { src = q_w2;  off = Q2_OFF;  K = 384; F = 384; }
        else if (i < M2_OFF) { src = m_w1;  off = M1_OFF;  K = 384; F = 256; }
        else if (i < M3_OFF) { src = m_w2;  off = M2_OFF;  K = 256; F = 256; }
        else                 { src = m_w3;  off = M3_OFF;  K = 256; F = 16;  }
        int t = i - off;
        int chunk = t >> 9, r = t & 511;
        int ln = r >> 5, kq = r & 31;
        int FT = F >> 4;
        int kc = chunk / FT, nt = chunk - kc * FT;
        int f = nt * 16 + ln, k = kc * 32 + kq;
        float v;
        if (off == M3_OFF) v = (f < 3) ? m_w3[f * 256 + k] : 0.f;
        else               v = src[(size_t)f * K + k];
        if (off == Q1_OFF) v *= q_ln_g[k];
        if (off == M1_OFF) v *= m_ln_g[k];
        ws[i] = f2bf(v);
        return;
    }
    int f = blk - NCONV;   // 0..639
    const float *Wsrc, *lng, *lnb, *bias; int fr, go, co;
    if (f < 384) { Wsrc = q_w1; lng = q_ln_g; lnb = q_ln_b; bias = q_b1; fr = f;      go = GQ_OFF; co = CQ_OFF; }
    else         { Wsrc = m_w1; lng = m_ln_g; lnb = m_ln_b; bias = m_b1; fr = f - 384; go = GM_OFF; co = CM_OFF; }
    float g = 0.f, c = 0.f;
    for (int k = tid; k < 384; k += 256) {
        float wv = Wsrc[(size_t)fr * 384 + k];
        g += bf2f(f2bf(wv * lng[k]));   // match MFMA's bf16-rounded weights
        c += wv * lnb[k];
    }
    #pragma unroll
    for (int d = 1; d < 64; d <<= 1) { g += __shfl_xor(g, d); c += __shfl_xor(c, d); }
    if ((tid & 63) == 0) { rg[tid >> 6] = g; rc[tid >> 6] = c; }
    __syncthreads();
    if (tid == 0) {
        cst[go + fr] = rg[0] + rg[1] + rg[2] + rg[3];
        cst[co + fr] = rc[0] + rc[1] + rc[2] + rc[3] + bias[fr];
    }
}

// In-place FC layer: single B buffer (loads issue behind the MFMA burst →
// ~1-burst lead), chunk-major layout → one uniform base + immediate offsets.
// Transposed D (weights as A-op): thread (q,ln) holds D[f][m=mt*16+ln].
// Register budget: acc 96 + B 24 + A 32 + misc ~15 → fits 3 blocks/CU.
template<int K, int FT, int NT, int NTN, bool SILU_, bool MASK, bool LNIN, bool STATS>
__device__ __attribute__((always_inline)) inline void layer_ip(
    const short* __restrict__ W, const float* __restrict__ cb,
    const float* __restrict__ Gf, int FB,
    const short* __restrict__ Wn, int FBn,
    bf16x8 (&bin)[6],
    short (*__restrict__ xs)[LDA],
    float (*__restrict__ sc1)[4], float (*__restrict__ sc2)[4],
    const float* __restrict__ wmask, int w, int q, int ln)
{
    constexpr int NK = K / 32;
    const int loff = ln * 32 + q * 8;
    const short* bw = W + (size_t)(FB / 16) * 512 + loff;   // wave slice base, chunk 0

    f32x4 acc[4][NT];
    #pragma unroll
    for (int mt = 0; mt < 4; ++mt)
        #pragma unroll
        for (int nt = 0; nt < NT; ++nt)
            acc[mt][nt] = (f32x4){0.f, 0.f, 0.f, 0.f};

    bf16x8 B[NT];
    #pragma unroll
    for (int nt = 0; nt < NT; ++nt) B[nt] = bin[nt];   // chunk 0 (cross-layer prefetch)

    #pragma unroll
    for (int kc = 0; kc < NK; ++kc) {
        bf16x8 a[4];
        #pragma unroll
        for (int mt = 0; mt < 4; ++mt)
            a[mt] = *(const bf16x8*)&xs[mt * 16 + ln][kc * 32 + q * 8];
        #pragma unroll
        for (int nt = 0; nt < NT; ++nt)
            #pragma unroll
            for (int mt = 0; mt < 4; ++mt)
                acc[mt][nt] = __builtin_amdgcn_mfma_f32_16x16x32_bf16(
                    B[nt], a[mt], acc[mt][nt], 0, 0, 0);
        if (kc + 1 < NK) {
            const short* cb_ = bw + (size_t)(kc + 1) * FT * 512;
            #pragma unroll
            for (int nt = 0; nt < NT; ++nt)
                B[nt] = *(const bf16x8*)(cb_ + nt * 512);   // nt*1024B imm offset
        }
    }

    // cross-layer prefetch of next layer's chunk 0 — BAR() keeps it in flight
    {
        const short* nb = Wn + (size_t)(FBn / 16) * 512 + loff;
        #pragma unroll
        for (int nt = 0; nt < NTN; ++nt)
            bin[nt] = *(const bf16x8*)(nb + nt * 512);
    }

    BAR();   // all reads of xs complete before any in-place write (lgkm only)

    float mk[4], rstd[4], rm[4];
    #pragma unroll
    for (int mt = 0; mt < 4; ++mt) {
        int m = mt * 16 + ln;
        if (MASK) mk[mt] = wmask[m];
        if (LNIN) {
            f32x4 p1 = *(const f32x4*)&sc1[m][0];
            f32x4 p2 = *(const f32x4*)&sc2[m][0];
            float t1 = p1[0] + p1[1] + p1[2] + p1[3];
            float t2 = p2[0] + p2[1] + p2[2] + p2[3];
            float mean = t1 * (1.f / 384.f);
            float var  = t2 * (1.f / 384.f) - mean * mean;
            rstd[mt] = rsqrtf(var + 1e-5f);
            rm[mt]   = rstd[mt] * mean;
        }
    }

    float s1[4] = {0.f,0.f,0.f,0.f}, s2[4] = {0.f,0.f,0.f,0.f};
    #pragma unroll
    for (int nt = 0; nt < NT; ++nt) {
        const int f0 = FB + nt * 16 + q * 4;
        f32x4 c4 = *(const f32x4*)&cb[f0];
        f32x4 g4;
        if (LNIN) g4 = *(const f32x4*)&Gf[f0];
        #pragma unroll
        for (int mt = 0; mt < 4; ++mt) {
            f32x4 vv;
            #pragma unroll
            for (int r = 0; r < 4; ++r) {
                float v;
                if (LNIN) v = fmaf(rstd[mt], acc[mt][nt][r], fmaf(-rm[mt], g4[r], c4[r]));
                else      v = acc[mt][nt][r] + c4[r];
                if (SILU_) v = silu(v);
                if (MASK) v *= mk[mt];
                if (STATS) { s1[mt] += v; s2[mt] += v * v; }
                vv[r] = v;
            }
            *(s16x4*)&xs[mt * 16 + ln][f0] = pack4(vv);
        }
    }
    if (STATS) {
        #pragma unroll
        for (int mt = 0; mt < 4; ++mt) {
            s1[mt] += __shfl_xor(s1[mt], 16); s2[mt] += __shfl_xor(s2[mt], 16);
            s1[mt] += __shfl_xor(s1[mt], 32); s2[mt] += __shfl_xor(s2[mt], 32);
        }
        if (q == 0) {
            #pragma unroll
            for (int mt = 0; mt < 4; ++mt) {
                sc1[mt * 16 + ln][w] = s1[mt];
                sc2[mt * 16 + ln][w] = s2[mt];
            }
        }
    }
    BAR();   // writes (xs and sc) visible before next layer
}

__global__ __launch_bounds__(256, 3) void upxi64(
    const float* __restrict__ s_parent, const float* __restrict__ mu_k,
    const float* __restrict__ R_k,      const float* __restrict__ s_k,
    const int*   __restrict__ a_idx,    const float* __restrict__ node_mask,
    const float* __restrict__ pos01,
    const float* __restrict__ pos_b,
    const float* __restrict__ q_b2,     const float* __restrict__ m_b2,
    const float* __restrict__ m_b3,
    const short* __restrict__ wsb,      const float* __restrict__ cst,
    float* __restrict__ out)
{
    __shared__ short xs[MB][LDA];
    __shared__ float sc1[MB][4];
    __shared__ float sc2[MB][4];
    __shared__ float wmask[MB], wpos[MB];
    __shared__ int   widx[MB];

    const int tid  = threadIdx.x;
    const int w    = tid >> 6;
    const int lane = tid & 63;
    const int q    = lane >> 4;
    const int ln   = lane & 15;

    const int g0 = blockIdx.x * MB;
    const int b  = g0 / Nn;
    const int n0 = g0 % Nn;

    // prefetch Q1 chunk 0 immediately (hidden under scalars+sincos+pos)
    bf16x8 bin[6];
    {
        const short* nb = wsb + Q1_OFF + (size_t)(w * 6) * 512 + ln * 32 + q * 8;
        #pragma unroll
        for (int nt = 0; nt < 6; ++nt)
            bin[nt] = *(const bf16x8*)(nb + nt * 512);
    }

    if (tid < MB) {
        int gi = b * Nn + n0 + tid;
        int idx = a_idx[gi];
        widx[tid]  = min(max(idx, 0), Kk - 1);
        wmask[tid] = node_mask[gi];
        wpos[tid]  = pos01[gi];
    }
    BAR();

    const float* gbase = s_parent + (long)b * Kk * C;

    // ---- pos layer (transposed D): pos_w as A-operand, feats as B-operand ----
    {
        const short* pos_wb = wsb + POS_OFF;
        const bool use_sin = (q < 2);
        const int kb = (q & 1) * 8;
        bf16x8 a[4];
        #pragma unroll
        for (int mt = 0; mt < 4; ++mt) {
            float p = wpos[mt * 16 + ln];
            #pragma unroll
            for (int e = 0; e < 8; ++e) {
                float fr = (float)(1 << (kb + e)) * 3.14159265358979323846f;
                float sv, cv;
                __sincosf(p * fr, &sv, &cv);
                a[mt][e] = f2bf(use_sin ? sv : cv);
            }
        }
        f32x4 acc[4][6];
        #pragma unroll
        for (int mt = 0; mt < 4; ++mt)
            #pragma unroll
            for (int nt = 0; nt < 6; ++nt)
                acc[mt][nt] = (f32x4){0.f, 0.f, 0.f, 0.f};
        #pragma unroll
        for (int nt = 0; nt < 6; ++nt) {
            bf16x8 bfr = *(const bf16x8*)&pos_wb[(w * 6 + nt) * 512 + ln * 32 + q * 8];
            #pragma unroll
            for (int mt = 0; mt < 4; ++mt)
                acc[mt][nt] = __builtin_amdgcn_mfma_f32_16x16x32_bf16(bfr, a[mt], acc[mt][nt], 0, 0, 0);
        }
        float mk[4]; int ix[4];
        #pragma unroll
        for (int mt = 0; mt < 4; ++mt) {
            mk[mt] = wmask[mt * 16 + ln];
            ix[mt] = widx[mt * 16 + ln];
        }
        float s1[4] = {0.f,0.f,0.f,0.f}, s2[4] = {0.f,0.f,0.f,0.f};
        #pragma unroll
        for (int nt = 0; nt < 6; ++nt) {
            const int f0 = w * 96 + nt * 16 + q * 4;
            f32x4 pb4 = *(const f32x4*)&pos_b[f0];
            #pragma unroll
            for (int mt = 0; mt < 4; ++mt) {
                f32x4 g4 = *(const f32x4*)&gbase[(long)ix[mt] * C + f0];
                f32x4 vv;
                #pragma unroll
                for (int r = 0; r < 4; ++r) {
                    float v = (acc[mt][nt][r] + pb4[r]) * mk[mt] + g4[r];
                    s1[mt] += v; s2[mt] += v * v;
                    vv[r] = v;
                }
                *(s16x4*)&xs[mt * 16 + ln][f0] = pack4(vv);
            }
        }
        #pragma unroll
        for (int mt = 0; mt < 4; ++mt) {
            s1[mt] += __shfl_xor(s1[mt], 16); s2[mt] += __shfl_xor(s2[mt], 16);
            s1[mt] += __shfl_xor(s1[mt], 32); s2[mt] += __shfl_xor(s2[mt], 32);
        }
        if (q == 0) {
            #pragma unroll
            for (int mt = 0; mt < 4; ++mt) {
                sc1[mt * 16 + ln][w] = s1[mt];
                sc2[mt * 16 + ln][w] = s2[mt];
            }
        }
    }
    BAR();

    // Q1: LN(q) folded: v = silu(rstd*acc - rm*Gq + Cq)
    layer_ip<384, 24, 6, 6, true,  false, true,  false>(wsb + Q1_OFF, cst + CQ_OFF,
        cst + GQ_OFF, w * 96, wsb + Q2_OFF, w * 96, bin, xs, sc1, sc2, wmask, w, q, ln);
    // Q2: (acc + b2)*mask, stats for m-LN
    layer_ip<384, 24, 6, 4, false, true,  false, true >(wsb + Q2_OFF, q_b2,
        nullptr, w * 96, wsb + M1_OFF, w * 64, bin, xs, sc1, sc2, wmask, w, q, ln);
    // M1: LN(m) folded: v = silu(rstd*acc - rm*Gm + Cm)
    layer_ip<384, 16, 4, 4, true,  false, true,  false>(wsb + M1_OFF, cst + CM_OFF,
        cst + GM_OFF, w * 64, wsb + M2_OFF, w * 64, bin, xs, sc1, sc2, wmask, w, q, ln);
    // M2: silu(acc + b2)
    layer_ip<256, 16, 4, 1, true,  false, false, false>(wsb + M2_OFF, m_b2,
        nullptr, w * 64, wsb + M3_OFF, 0, bin, xs, sc1, sc2, wmask, w, q, ln);

    // ---- tail: 256->3 MFMA transposed (wave w owns m-tile w), tanh*1.5 ----
    {
        const short* W3 = wsb + M3_OFF;   // F=16 -> FT=1, chunk kc at kc*512
        f32x4 a3 = (f32x4){0.f, 0.f, 0.f, 0.f};
        #pragma unroll
        for (int kc = 0; kc < 8; ++kc) {
            bf16x8 a  = *(const bf16x8*)&xs[w * 16 + ln][kc * 32 + q * 8];
            bf16x8 bf = (kc == 0) ? bin[0]
                      : *(const bf16x8*)(W3 + kc * 512 + ln * 32 + q * 8);
            a3 = __builtin_amdgcn_mfma_f32_16x16x32_bf16(bf, a, a3, 0, 0, 0);
        }
        if (q == 0) {
            int m = w * 16 + ln;
            float mkv = wmask[m];
            #pragma unroll
            for (int r = 0; r < 3; ++r) {
                float v = (a3[r] + m_b3[r]) * mkv;
                sc1[m][r] = tanhf(v) * 1.5f;
            }
        }
    }

    // ---- rigid apply + outputs (same-wave lanes; in-wave order suffices) ----
    if (lane < 16) {
        int m = w * 16 + lane;
        long gi = (long)b * Nn + n0 + m;
        long pk = (long)b * Kk + widx[m];
        float mkv = wmask[m];
        float xv[3], yv[3], xiv[3];
        #pragma unroll
        for (int j = 0; j < 3; ++j) {
            xiv[j] = sc1[m][j];
            float sc = fmaxf(s_k[pk * 3 + j], 1e-8f);
            xv[j] = xiv[j] * sc;
        }
        #pragma unroll
        for (int i = 0; i < 3; ++i) {
            float a = R_k[pk * 9 + i * 3 + 0] * xv[0]
                    + R_k[pk * 9 + i * 3 + 1] * xv[1]
                    + R_k[pk * 9 + i * 3 + 2] * xv[2]
                    + mu_k[pk * 3 + i];
            yv[i] = a * mkv * 10.f;
        }
        float* o0 = out;
        float* o1 = out + (long)Bb * Nn * 3;
        float* o2 = out + (long)Bb * Nn * 6;
        #pragma unroll
        for (int j = 0; j < 3; ++j) { o0[gi * 3 + j] = xiv[j]; o1[gi * 3 + j] = yv[j]; }
        o2[gi] = wpos[m];
    }
}

extern "C" void kernel_launch(void* const* d_in, const int* in_sizes, int n_in,
                              void* d_out, int out_size, void* d_ws, size_t ws_size,
                              hipStream_t stream) {
    const float* s_parent = (const float*)d_in[0];
    const float* mu_k     = (const float*)d_in[1];
    const float* R_k      = (const float*)d_in[2];
    const float* s_k      = (const float*)d_in[3];
    const int*   a_idx    = (const int*)  d_in[4];
    const float* node_mask= (const float*)d_in[5];
    const float* pos01    = (const float*)d_in[6];
    const float* pos_w    = (const float*)d_in[7];
    const float* pos_b    = (const float*)d_in[8];
    const float* q_ln_g   = (const float*)d_in[9];
    const float* q_ln_b   = (const float*)d_in[10];
    const float* q_w1     = (const float*)d_in[11];
    const float* q_b1     = (const float*)d_in[12];
    const float* q_w2     = (const float*)d_in[13];
    const float* q_b2     = (const float*)d_in[14];
    const float* m_ln_g   = (const float*)d_in[15];
    const float* m_ln_b   = (const float*)d_in[16];
    const float* m_w1     = (const float*)d_in[17];
    const float* m_b1     = (const float*)d_in[18];
    const float* m_w2     = (const float*)d_in[19];
    const float* m_b2     = (const float*)d_in[20];
    const float* m_w3     = (const float*)d_in[21];
    const float* m_b3     = (const float*)d_in[22];

    short* wsb = (short*)d_ws;
    float* cst = (float*)(wsb + W_TOTAL);

    prep<<<NCONV + 640, 256, 0, stream>>>(
        pos_w, q_w1, q_w2, m_w1, m_w2, m_w3,
        q_ln_g, q_ln_b, m_ln_g, m_ln_b, q_b1, m_b1, wsb, cst);

    int blocks = (Bb * Nn) / MB;  // 1024
    upxi64<<<blocks, 256, 0, stream>>>(
        s_parent, mu_k, R_k, s_k, a_idx, node_mask, pos01,
        pos_b, q_b2, m_b2, m_b3, wsb, cst, (float*)d_out);
}

// Round 15
// 191.981 us; speedup vs baseline: 1.1552x; 1.0619x over previous
//
#include <hip/hip_runtime.h>
#include <hip/hip_bf16.h>
#include <math.h>

#define C 384
#define NF 16
#define H 256
#define Bb 4
#define Kk 2048
#define Nn 16384
#define MB 64           // nodes per block (4 m-tiles)
#define LDA 392         // act row stride in shorts

typedef __attribute__((ext_vector_type(8))) short bf16x8;
typedef __attribute__((ext_vector_type(4))) float f32x4;
typedef __attribute__((ext_vector_type(4))) short s16x4;

// ws layout (shorts), fragment-linear: [ntile][kchunk][ln(16)][kq(32)]
#define POS_OFF 0            // pos_w  F=384 K=32
#define Q1_OFF  12288        // q_w1*q_ln_g   F=384 K=384
#define Q2_OFF  159744       // q_w2          F=384 K=384
#define M1_OFF  307200       // m_w1*m_ln_g   F=256 K=384
#define M2_OFF  405504       // m_w2          F=256 K=256
#define M3_OFF  471040       // m_w3 padded [16][256]
#define W_TOTAL 475136
#define NCONV   (W_TOTAL / 512)   // 928 blocks, 2 elems/thread
// float constants after the shorts
#define GQ_OFF 0
#define CQ_OFF 384
#define GM_OFF 768
#define CM_OFF 1024

// barrier that does NOT drain vmcnt — weight prefetches stay in flight.
#define BAR() __asm__ volatile("s_waitcnt lgkmcnt(0)\ns_barrier" ::: "memory")

__device__ __attribute__((always_inline)) inline short f2bf(float x) {
    return __builtin_bit_cast(short, __float2bfloat16(x));
}
__device__ __attribute__((always_inline)) inline float bf2f(short s) {
    return __bfloat162float(__builtin_bit_cast(__hip_bfloat16, s));
}
__device__ __attribute__((always_inline)) inline float silu(float v) {
    return v * __builtin_amdgcn_rcpf(1.f + __expf(-v));
}
__device__ __attribute__((always_inline)) inline s16x4 pack4(f32x4 v) {
    __hip_bfloat162 p0 = __float22bfloat162_rn(float2{v[0], v[1]});
    __hip_bfloat162 p1 = __float22bfloat162_rn(float2{v[2], v[3]});
    s16x4 o;
    o[0] = __builtin_bit_cast(short, p0.x);
    o[1] = __builtin_bit_cast(short, p0.y);
    o[2] = __builtin_bit_cast(short, p1.x);
    o[3] = __builtin_bit_cast(short, p1.y);
    return o;
}

// ---- prep: weight f32->bf16 fragment swizzle (2 elems/thread) + LN-const fold ----
__global__ __launch_bounds__(256) void prep(
    const float* __restrict__ pos_w, const float* __restrict__ q_w1,
    const float* __restrict__ q_w2,  const float* __restrict__ m_w1,
    const float* __restrict__ m_w2,  const float* __restrict__ m_w3,
    const float* __restrict__ q_ln_g, const float* __restrict__ q_ln_b,
    const float* __restrict__ m_ln_g, const float* __restrict__ m_ln_b,
    const float* __restrict__ q_b1,   const float* __restrict__ m_b1,
    short* __restrict__ ws, float* __restrict__ cst)
{
    __shared__ float rg[4], rc[4];
    int tid = threadIdx.x;
    int blk = blockIdx.x;
    if (blk < NCONV) {
        int i = (blk * 256 + tid) * 2;       // even; pair (i, i+1) same chunk row
        const float* src; int off, K;
        if      (i < Q1_OFF) { src = pos_w; off = POS_OFF; K = 32; }
        else if (i < Q2_OFF) { src = q_w1;  off = Q1_OFF;  K = 384; }
        else if (i < M1_OFF) { src = q_w2;  off = Q2_OFF;  K = 384; }
        else if (i < M2_OFF) { src = m_w1;  off = M1_OFF;  K = 384; }
        else if (i < M3_OFF) { src = m_w2;  off = M2_OFF;  K = 256; }
        else                 { src = m_w3;  off = M3_OFF;  K = 256; }
        int t = i - off;
        int chunk = t >> 9, r = t & 511;
        int ln = r >> 5, kq = r & 31;        // kq even; kq+1 in same group
        int NKm = K >> 5;
        int ntg = chunk / NKm, kk = chunk - ntg * NKm;
        int f = ntg * 16 + ln, k = kk * 32 + kq;
        float v0, v1;
        if (off == M3_OFF) {
            v0 = (f < 3) ? m_w3[f * 256 + k]     : 0.f;
            v1 = (f < 3) ? m_w3[f * 256 + k + 1] : 0.f;
        } else {
            float2 v2 = *(const float2*)&src[(size_t)f * K + k];
            v0 = v2.x; v1 = v2.y;
        }
        if (off == Q1_OFF) { v0 *= q_ln_g[k]; v1 *= q_ln_g[k + 1]; }
        if (off == M1_OFF) { v0 *= m_ln_g[k]; v1 *= m_ln_g[k + 1]; }
        unsigned pk = ((unsigned)(unsigned short)f2bf(v0)) |
                      (((unsigned)(unsigned short)f2bf(v1)) << 16);
        *(unsigned*)&ws[i] = pk;
        return;
    }
    int f = blk - NCONV;   // 0..639
    const float *Wsrc, *lng, *lnb, *bias; int fr, go, co;
    if (f < 384) { Wsrc = q_w1; lng = q_ln_g; lnb = q_ln_b; bias = q_b1; fr = f;      go = GQ_OFF; co = CQ_OFF; }
    else         { Wsrc = m_w1; lng = m_ln_g; lnb = m_ln_b; bias = m_b1; fr = f - 384; go = GM_OFF; co = CM_OFF; }
    float g = 0.f, c = 0.f;
    for (int k = tid; k < 384; k += 256) {
        float wv = Wsrc[(size_t)fr * 384 + k];
        g += bf2f(f2bf(wv * lng[k]));   // match MFMA's bf16-rounded weights
        c += wv * lnb[k];
    }
    #pragma unroll
    for (int d = 1; d < 64; d <<= 1) { g += __shfl_xor(g, d); c += __shfl_xor(c, d); }
    if ((tid & 63) == 0) { rg[tid >> 6] = g; rc[tid >> 6] = c; }
    __syncthreads();
    if (tid == 0) {
        cst[go + fr] = rg[0] + rg[1] + rg[2] + rg[3];
        cst[co + fr] = rc[0] + rc[1] + rc[2] + rc[3] + bias[fr];
    }
}

// In-place FC layer: R8/R12-proven kc+=2 double-step (two B buffers — no
// spill), cross-layer bin prefetch rides through BAR(). Transposed D (weights
// as A-operand): thread (q,ln) holds D[f=FB+nt*16+q*4+r][m=mt*16+ln].
template<int K, int NT, int NTN, int KN, bool SILU_, bool MASK, bool LNIN, bool STATS>
__device__ __attribute__((always_inline)) inline void layer_ip(
    const short* __restrict__ W, const float* __restrict__ cb,
    const float* __restrict__ Gf, int FB,
    const short* __restrict__ Wn, int FBn,
    bf16x8 (&bin)[6],
    short (*__restrict__ xs)[LDA],
    float (*__restrict__ sc1)[4], float (*__restrict__ sc2)[4],
    const float* __restrict__ wmask, int w, int q, int ln)
{
    constexpr int NK = K / 32;
    const short* bp[NT];
    #pragma unroll
    for (int nt = 0; nt < NT; ++nt)
        bp[nt] = W + ((size_t)(FB / 16 + nt) * NK) * 512 + ln * 32 + q * 8;

    f32x4 acc[4][NT];
    #pragma unroll
    for (int mt = 0; mt < 4; ++mt)
        #pragma unroll
        for (int nt = 0; nt < NT; ++nt)
            acc[mt][nt] = (f32x4){0.f, 0.f, 0.f, 0.f};

    bf16x8 b0[NT], b1[NT], a0[4], a1[4];
    #pragma unroll
    for (int nt = 0; nt < NT; ++nt) b0[nt] = bin[nt];   // prefetched first chunk
    #pragma unroll
    for (int mt = 0; mt < 4; ++mt) a0[mt] = *(const bf16x8*)&xs[mt * 16 + ln][q * 8];

    #pragma unroll
    for (int kc = 0; kc < NK; kc += 2) {
        #pragma unroll
        for (int nt = 0; nt < NT; ++nt) b1[nt] = *(const bf16x8*)(bp[nt] + (kc + 1) * 512);
        #pragma unroll
        for (int mt = 0; mt < 4; ++mt) a1[mt] = *(const bf16x8*)&xs[mt * 16 + ln][(kc + 1) * 32 + q * 8];
        #pragma unroll
        for (int nt = 0; nt < NT; ++nt)
            #pragma unroll
            for (int mt = 0; mt < 4; ++mt)
                acc[mt][nt] = __builtin_amdgcn_mfma_f32_16x16x32_bf16(b0[nt], a0[mt], acc[mt][nt], 0, 0, 0);
        if (kc + 2 < NK) {
            #pragma unroll
            for (int nt = 0; nt < NT; ++nt) b0[nt] = *(const bf16x8*)(bp[nt] + (kc + 2) * 512);
            #pragma unroll
            for (int mt = 0; mt < 4; ++mt) a0[mt] = *(const bf16x8*)&xs[mt * 16 + ln][(kc + 2) * 32 + q * 8];
        }
        #pragma unroll
        for (int nt = 0; nt < NT; ++nt)
            #pragma unroll
            for (int mt = 0; mt < 4; ++mt)
                acc[mt][nt] = __builtin_amdgcn_mfma_f32_16x16x32_bf16(b1[nt], a1[mt], acc[mt][nt], 0, 0, 0);
    }

    // prefetch NEXT layer's first k-chunk — BAR() keeps it in flight
    #pragma unroll
    for (int nt = 0; nt < NTN; ++nt)
        bin[nt] = *(const bf16x8*)(Wn + ((size_t)(FBn / 16 + nt) * (KN / 32)) * 512 + ln * 32 + q * 8);

    BAR();   // all reads of xs complete before any in-place write (lgkm only)

    float mk[4], rstd[4], rm[4];
    #pragma unroll
    for (int mt = 0; mt < 4; ++mt) {
        int m = mt * 16 + ln;
        if (MASK) mk[mt] = wmask[m];
        if (LNIN) {
            f32x4 p1 = *(const f32x4*)&sc1[m][0];
            f32x4 p2 = *(const f32x4*)&sc2[m][0];
            float t1 = p1[0] + p1[1] + p1[2] + p1[3];
            float t2 = p2[0] + p2[1] + p2[2] + p2[3];
            float mean = t1 * (1.f / 384.f);
            float var  = t2 * (1.f / 384.f) - mean * mean;
            rstd[mt] = rsqrtf(var + 1e-5f);
            rm[mt]   = rstd[mt] * mean;
        }
    }

    float s1[4] = {0.f,0.f,0.f,0.f}, s2[4] = {0.f,0.f,0.f,0.f};
    #pragma unroll
    for (int nt = 0; nt < NT; ++nt) {
        const int f0 = FB + nt * 16 + q * 4;
        f32x4 c4 = *(const f32x4*)&cb[f0];
        f32x4 g4;
        if (LNIN) g4 = *(const f32x4*)&Gf[f0];
        #pragma unroll
        for (int mt = 0; mt < 4; ++mt) {
            f32x4 vv;
            #pragma unroll
            for (int r = 0; r < 4; ++r) {
                float v;
                if (LNIN) v = fmaf(rstd[mt], acc[mt][nt][r], fmaf(-rm[mt], g4[r], c4[r]));
                else      v = acc[mt][nt][r] + c4[r];
                if (SILU_) v = silu(v);
                if (MASK) v *= mk[mt];
                if (STATS) { s1[mt] += v; s2[mt] += v * v; }
                vv[r] = v;
            }
            *(s16x4*)&xs[mt * 16 + ln][f0] = pack4(vv);
        }
    }
    if (STATS) {
        #pragma unroll
        for (int mt = 0; mt < 4; ++mt) {
            s1[mt] += __shfl_xor(s1[mt], 16); s2[mt] += __shfl_xor(s2[mt], 16);
            s1[mt] += __shfl_xor(s1[mt], 32); s2[mt] += __shfl_xor(s2[mt], 32);
        }
        if (q == 0) {
            #pragma unroll
            for (int mt = 0; mt < 4; ++mt) {
                sc1[mt * 16 + ln][w] = s1[mt];
                sc2[mt * 16 + ln][w] = s2[mt];
            }
        }
    }
    BAR();   // writes (xs and sc) visible before next layer
}

__global__ __launch_bounds__(256, 2) void upxi64(
    const float* __restrict__ s_parent, const float* __restrict__ mu_k,
    const float* __restrict__ R_k,      const float* __restrict__ s_k,
    const int*   __restrict__ a_idx,    const float* __restrict__ node_mask,
    const float* __restrict__ pos01,
    const float* __restrict__ pos_b,
    const float* __restrict__ q_b2,     const float* __restrict__ m_b2,
    const float* __restrict__ m_b3,
    const short* __restrict__ wsb,      const float* __restrict__ cst,
    float* __restrict__ out)
{
    __shared__ short xs[MB][LDA];
    __shared__ float sc1[MB][4];
    __shared__ float sc2[MB][4];
    __shared__ float wmask[MB], wpos[MB];
    __shared__ int   widx[MB];

    const int tid  = threadIdx.x;
    const int w    = tid >> 6;
    const int lane = tid & 63;
    const int q    = lane >> 4;
    const int ln   = lane & 15;

    const int g0 = blockIdx.x * MB;
    const int b  = g0 / Nn;
    const int n0 = g0 % Nn;

    // prefetch Q1 first k-chunk immediately (hidden under scalars+sincos+pos)
    bf16x8 bin[6];
    #pragma unroll
    for (int nt = 0; nt < 6; ++nt)
        bin[nt] = *(const bf16x8*)(wsb + Q1_OFF + ((size_t)(w * 6 + nt) * 12) * 512 + ln * 32 + q * 8);

    // per-wave redundant scalar loads (registers) — removes the first barrier.
    // wave 0 additionally populates the LDS copies consumed much later (tail,
    // Q2 mask) — visibility guaranteed by the 9 intervening barriers.
    int   ix[4]; float mk0[4], pv[4];
    {
        const int gi0 = b * Nn + n0;
        #pragma unroll
        for (int mt = 0; mt < 4; ++mt) {
            int m = mt * 16 + ln;
            int idx = a_idx[gi0 + m];
            ix[mt]  = min(max(idx, 0), Kk - 1);
            mk0[mt] = node_mask[gi0 + m];
            pv[mt]  = pos01[gi0 + m];
        }
        if (w == 0) {
            int gi = gi0 + lane;
            int idx = a_idx[gi];
            widx[lane]  = min(max(idx, 0), Kk - 1);
            wmask[lane] = node_mask[gi];
            wpos[lane]  = pos01[gi];
        }
    }

    const float* gbase = s_parent + (long)b * Kk * C;

    // ---- pos layer (transposed D): pos_w as A-operand, feats as B-operand ----
    {
        const short* pos_wb = wsb + POS_OFF;
        const bool use_sin = (q < 2);
        const int kb = (q & 1) * 8;
        bf16x8 a[4];
        #pragma unroll
        for (int mt = 0; mt < 4; ++mt) {
            float p = pv[mt];
            #pragma unroll
            for (int e = 0; e < 8; ++e) {
                float fr = (float)(1 << (kb + e)) * 3.14159265358979323846f;
                float sv, cv;
                __sincosf(p * fr, &sv, &cv);
                a[mt][e] = f2bf(use_sin ? sv : cv);
            }
        }
        f32x4 acc[4][6];
        #pragma unroll
        for (int mt = 0; mt < 4; ++mt)
            #pragma unroll
            for (int nt = 0; nt < 6; ++nt)
                acc[mt][nt] = (f32x4){0.f, 0.f, 0.f, 0.f};
        #pragma unroll
        for (int nt = 0; nt < 6; ++nt) {
            bf16x8 bfr = *(const bf16x8*)&pos_wb[(w * 6 + nt) * 512 + ln * 32 + q * 8];
            #pragma unroll
            for (int mt = 0; mt < 4; ++mt)
                acc[mt][nt] = __builtin_amdgcn_mfma_f32_16x16x32_bf16(bfr, a[mt], acc[mt][nt], 0, 0, 0);
        }
        float s1[4] = {0.f,0.f,0.f,0.f}, s2[4] = {0.f,0.f,0.f,0.f};
        #pragma unroll
        for (int nt = 0; nt < 6; ++nt) {
            const int f0 = w * 96 + nt * 16 + q * 4;
            f32x4 pb4 = *(const f32x4*)&pos_b[f0];
            #pragma unroll
            for (int mt = 0; mt < 4; ++mt) {
                f32x4 g4 = *(const f32x4*)&gbase[(long)ix[mt] * C + f0];
                f32x4 vv;
                #pragma unroll
                for (int r = 0; r < 4; ++r) {
                    float v = (acc[mt][nt][r] + pb4[r]) * mk0[mt] + g4[r];
                    s1[mt] += v; s2[mt] += v * v;
                    vv[r] = v;
                }
                *(s16x4*)&xs[mt * 16 + ln][f0] = pack4(vv);
            }
        }
        #pragma unroll
        for (int mt = 0; mt < 4; ++mt) {
            s1[mt] += __shfl_xor(s1[mt], 16); s2[mt] += __shfl_xor(s2[mt], 16);
            s1[mt] += __shfl_xor(s1[mt], 32); s2[mt] += __shfl_xor(s2[mt], 32);
        }
        if (q == 0) {
            #pragma unroll
            for (int mt = 0; mt < 4; ++mt) {
                sc1[mt * 16 + ln][w] = s1[mt];
                sc2[mt * 16 + ln][w] = s2[mt];
            }
        }
    }
    BAR();

    // Q1: LN(q) folded: v = silu(rstd*acc - rm*Gq + Cq)
    layer_ip<384, 6, 6, 384, true,  false, true,  false>(wsb + Q1_OFF, cst + CQ_OFF,
        cst + GQ_OFF, w * 96, wsb + Q2_OFF, w * 96, bin, xs, sc1, sc2, wmask, w, q, ln);
    // Q2: (acc + b2)*mask, stats for m-LN
    layer_ip<384, 6, 4, 384, false, true,  false, true >(wsb + Q2_OFF, q_b2,
        nullptr, w * 96, wsb + M1_OFF, w * 64, bin, xs, sc1, sc2, wmask, w, q, ln);
    // M1: LN(m) folded: v = silu(rstd*acc - rm*Gm + Cm)
    layer_ip<384, 4, 4, 256, true,  false, true,  false>(wsb + M1_OFF, cst + CM_OFF,
        cst + GM_OFF, w * 64, wsb + M2_OFF, w * 64, bin, xs, sc1, sc2, wmask, w, q, ln);
    // M2: silu(acc + b2)
    layer_ip<256, 4, 1, 256, true,  false, false, false>(wsb + M2_OFF, m_b2,
        nullptr, w * 64, wsb + M3_OFF, 0, bin, xs, sc1, sc2, wmask, w, q, ln);

    // ---- tail: 256->3 MFMA transposed (wave w owns m-tile w), tanh*1.5 ----
    {
        const short* W3 = wsb + M3_OFF;
        f32x4 a3 = (f32x4){0.f, 0.f, 0.f, 0.f};
        #pragma unroll
        for (int kc = 0; kc < 8; ++kc) {
            bf16x8 a  = *(const bf16x8*)&xs[w * 16 + ln][kc * 32 + q * 8];
            bf16x8 bf = (kc == 0) ? bin[0]
                      : *(const bf16x8*)(W3 + kc * 512 + ln * 32 + q * 8);
            a3 = __builtin_amdgcn_mfma_f32_16x16x32_bf16(bf, a, a3, 0, 0, 0);
        }
        if (q == 0) {
            int m = w * 16 + ln;
            float mkv = wmask[m];
            #pragma unroll
            for (int r = 0; r < 3; ++r) {
                float v = (a3[r] + m_b3[r]) * mkv;
                sc1[m][r] = tanhf(v) * 1.5f;
            }
        }
    }

    // ---- rigid apply + outputs (same-wave lanes; in-wave order suffices) ----
    if (lane < 16) {
        int m = w * 16 + lane;
        long gi = (long)b * Nn + n0 + m;
        long pk = (long)b * Kk + widx[m];
        float mkv = wmask[m];
        float xv[3], yv[3], xiv[3];
        #pragma unroll
        for (int j = 0; j < 3; ++j) {
            xiv[j] = sc1[m][j];
            float sc = fmaxf(s_k[pk * 3 + j], 1e-8f);
            xv[j] = xiv[j] * sc;
        }
        #pragma unroll
        for (int i = 0; i < 3; ++i) {
            float a = R_k[pk * 9 + i * 3 + 0] * xv[0]
                    + R_k[pk * 9 + i * 3 + 1] * xv[1]
                    + R_k[pk * 9 + i * 3 + 2] * xv[2]
                    + mu_k[pk * 3 + i];
            yv[i] = a * mkv * 10.f;
        }
        float* o0 = out;
        float* o1 = out + (long)Bb * Nn * 3;
        float* o2 = out + (long)Bb * Nn * 6;
        #pragma unroll
        for (int j = 0; j < 3; ++j) { o0[gi * 3 + j] = xiv[j]; o1[gi * 3 + j] = yv[j]; }
        o2[gi] = wpos[m];
    }
}

extern "C" void kernel_launch(void* const* d_in, const int* in_sizes, int n_in,
                              void* d_out, int out_size, void* d_ws, size_t ws_size,
                              hipStream_t stream) {
    const float* s_parent = (const float*)d_in[0];
    const float* mu_k     = (const float*)d_in[1];
    const float* R_k      = (const float*)d_in[2];
    const float* s_k      = (const float*)d_in[3];
    const int*   a_idx    = (const int*)  d_in[4];
    const float* node_mask= (const float*)d_in[5];
    const float* pos01    = (const float*)d_in[6];
    const float* pos_w    = (const float*)d_in[7];
    const float* pos_b    = (const float*)d_in[8];
    const float* q_ln_g   = (const float*)d_in[9];
    const float* q_ln_b   = (const float*)d_in[10];
    const float* q_w1     = (const float*)d_in[11];
    const float* q_b1     = (const float*)d_in[12];
    const float* q_w2     = (const float*)d_in[13];
    const float* q_b2     = (const float*)d_in[14];
    const float* m_ln_g   = (const float*)d_in[15];
    const float* m_ln_b   = (const float*)d_in[16];
    const float* m_w1     = (const float*)d_in[17];
    const float* m_b1     = (const float*)d_in[18];
    const float* m_w2     = (const float*)d_in[19];
    const float* m_b2     = (const float*)d_in[20];
    const float* m_w3     = (const float*)d_in[21];
    const float* m_b3     = (const float*)d_in[22];

    short* wsb = (short*)d_ws;
    float* cst = (float*)(wsb + W_TOTAL);

    prep<<<NCONV + 640, 256, 0, stream>>>(
        pos_w, q_w1, q_w2, m_w1, m_w2, m_w3,
        q_ln_g, q_ln_b, m_ln_g, m_ln_b, q_b1, m_b1, wsb, cst);

    int blocks = (Bb * Nn) / MB;  // 1024
    upxi64<<<blocks, 256, 0, stream>>>(
        s_parent, mu_k, R_k, s_k, a_idx, node_mask, pos01,
        pos_b, q_b2, m_b2, m_b3, wsb, cst, (float*)d_out);
}